// Round 1
// baseline (20287.724 us; speedup 1.0000x reference)
//
#include <hip/hip_runtime.h>
#include <math.h>

#define En 256
#define Hn 512
#define Bn 64
#define Sn 40
#define Tn 40
#define VTn 32000
#define Rn (Tn*Bn)
#define NVB 250   // 32000 / 128

__device__ __forceinline__ float dot4(float4 a, float4 b){
  return a.x*b.x + a.y*b.y + a.z*b.z + a.w*b.w;
}
__device__ __forceinline__ float sigm(float x){ return 1.f/(1.f+__expf(-x)); }

__global__ void zero_f4(float4* p, int n4){
  int i = blockIdx.x*blockDim.x+threadIdx.x;
  if (i<n4) p[i]=make_float4(0.f,0.f,0.f,0.f);
}

// X[b,s,:] = src_emb[src[b,s]]; Xr[b,s,:] = (len-1-s >= 0) ? src_emb[src[b,len-1-s]] : 0
__global__ void embed_src(const int* __restrict__ src, const int* __restrict__ lens,
                          const float* __restrict__ emb, float* __restrict__ X,
                          float* __restrict__ Xr){
  int idx = blockIdx.x*blockDim.x+threadIdx.x;
  const int tot = Bn*Sn*(En/4);
  if (idx>=tot) return;
  int e4 = idx % (En/4);
  int bs = idx / (En/4);
  int s = bs % Sn, b = bs / Sn;
  int tok = src[b*Sn+s];
  ((float4*)X)[idx] = ((const float4*)(emb + (size_t)tok*En))[e4];
  int len = lens[b];
  int j = len-1-s;
  float4 v = make_float4(0.f,0.f,0.f,0.f);
  if (j>=0){
    int tokr = src[b*Sn+j];
    v = ((const float4*)(emb + (size_t)tokr*En))[e4];
  }
  ((float4*)Xr)[idx] = v;
}

// one encoder LSTM step: thread = (b,u). gates i,f,g,o rows u, H+u, 2H+u, 3H+u.
__global__ void enc_lstm_step(const float* __restrict__ X, const float* __restrict__ Wih,
                              const float* __restrict__ Whh, const float* __restrict__ bias,
                              const float* __restrict__ h_in, float* __restrict__ h_out,
                              float* __restrict__ c, float* __restrict__ out, int out_ld,
                              const int* __restrict__ lens, int s){
  int tid = blockIdx.x*blockDim.x+threadIdx.x;   // Bn*Hn threads
  int u = tid % Hn, b = tid / Hn;
  const float4* xrow = (const float4*)(X + ((size_t)(b*Sn+s))*En);
  const float4* hrow = (const float4*)(h_in + (size_t)b*Hn);
  float g[4];
#pragma unroll
  for (int gi=0; gi<4; ++gi){
    int row = gi*Hn + u;
    float acc = bias[row];
    const float4* wi = (const float4*)(Wih + (size_t)row*En);
#pragma unroll 4
    for (int k=0;k<En/4;++k) acc += dot4(xrow[k], wi[k]);
    const float4* wh = (const float4*)(Whh + (size_t)row*Hn);
#pragma unroll 4
    for (int k=0;k<Hn/4;++k) acc += dot4(hrow[k], wh[k]);
    g[gi]=acc;
  }
  float ig = sigm(g[0]), fg = sigm(g[1]), gg = tanhf(g[2]), og = sigm(g[3]);
  float cp = c[tid];
  float cn = fg*cp + ig*gg;
  float hn = og*tanhf(cn);
  bool valid = s < lens[b];
  h_out[tid] = valid ? hn : h_in[tid];
  c[tid]    = valid ? cn : cp;
  out[((size_t)(b*Sn+s))*out_ld + u] = valid ? hn : 0.f;
}

// out_b written into encH[...,Hn:2Hn]: encH[b,s,H+u] = (s<len) ? outR[b,len-1-s,u] : 0
__global__ void reverse_bwd(const float* __restrict__ outR, const int* __restrict__ lens,
                            float* __restrict__ encH){
  int idx = blockIdx.x*blockDim.x+threadIdx.x;
  const int tot = Bn*Sn*(Hn/4);
  if (idx>=tot) return;
  int u4 = idx % (Hn/4);
  int bs = idx / (Hn/4);
  int s = bs % Sn, b = bs / Sn;
  int len = lens[b];
  float4 v = make_float4(0.f,0.f,0.f,0.f);
  if (s < len){
    int j = len-1-s;
    v = ((const float4*)(outR + ((size_t)(b*Sn+j))*Hn))[u4];
  }
  ((float4*)(encH + ((size_t)(b*Sn+s))*2*Hn + Hn))[u4] = v;
}

// y[b,u] = bias[u] + dot(concat(x1[b],x2[b]), W[u,:2H])
__global__ void proj_cat(const float* __restrict__ x1, const float* __restrict__ x2,
                         const float* __restrict__ W, const float* __restrict__ bias,
                         float* __restrict__ y){
  int tid = blockIdx.x*blockDim.x+threadIdx.x;   // Bn*Hn
  int u = tid % Hn, b = tid / Hn;
  float acc = bias[u];
  const float4* a1 = (const float4*)(x1 + (size_t)b*Hn);
  const float4* a2 = (const float4*)(x2 + (size_t)b*Hn);
  const float4* w  = (const float4*)(W + (size_t)u*2*Hn);
#pragma unroll 4
  for (int k=0;k<Hn/4;++k) acc += dot4(a1[k], w[k]);
#pragma unroll 4
  for (int k=0;k<Hn/4;++k) acc += dot4(a2[k], w[Hn/4+k]);
  y[tid]=acc;
}

// proj[b,s,u] = batt[u] + dot(encH[b,s,:], Watt[u,:])
__global__ void enc_proj_k(const float* __restrict__ encH, const float* __restrict__ Watt,
                           const float* __restrict__ batt, float* __restrict__ proj){
  int tid = blockIdx.x*blockDim.x+threadIdx.x;   // Bn*Sn*Hn
  int u = tid % Hn;
  size_t bs = (size_t)(tid / Hn);
  float acc = batt[u];
  const float4* x = (const float4*)(encH + bs*2*Hn);
  const float4* w = (const float4*)(Watt + (size_t)u*2*Hn);
#pragma unroll 4
  for (int k=0;k<2*Hn/4;++k) acc += dot4(x[k], w[k]);
  proj[tid] = acc;
}

// decoder LSTM step. ybar = [tgt_emb[tgt[b,t]] (E), o_prev[b] (H)]
__global__ void dec_lstm_step(const int* __restrict__ tgt, const float* __restrict__ temb,
                              const float* __restrict__ o_prev,
                              const float* __restrict__ Wih, const float* __restrict__ Whh,
                              const float* __restrict__ bias,
                              const float* __restrict__ h_in, float* __restrict__ h_out,
                              float* __restrict__ c, int t){
  int tid = blockIdx.x*blockDim.x+threadIdx.x;   // Bn*Hn
  int u = tid % Hn, b = tid / Hn;
  int tok = tgt[b*Tn + t];
  const float4* yrow = (const float4*)(temb + (size_t)tok*En);
  const float4* orow = (const float4*)(o_prev + (size_t)b*Hn);
  const float4* hrow = (const float4*)(h_in + (size_t)b*Hn);
  const int LD = En + Hn;   // 768
  float g[4];
#pragma unroll
  for (int gi=0; gi<4; ++gi){
    int row = gi*Hn + u;
    float acc = bias[row];
    const float4* wi = (const float4*)(Wih + (size_t)row*LD);
#pragma unroll 4
    for (int k=0;k<En/4;++k) acc += dot4(yrow[k], wi[k]);
#pragma unroll 4
    for (int k=0;k<Hn/4;++k) acc += dot4(orow[k], wi[En/4+k]);
    const float4* wh = (const float4*)(Whh + (size_t)row*Hn);
#pragma unroll 4
    for (int k=0;k<Hn/4;++k) acc += dot4(hrow[k], wh[k]);
    g[gi]=acc;
  }
  float ig = sigm(g[0]), fg = sigm(g[1]), gg = tanhf(g[2]), og = sigm(g[3]);
  float cp = c[tid];
  float cn = fg*cp + ig*gg;
  float hn = og*tanhf(cn);
  h_out[tid] = hn;
  c[tid] = cn;
}

// e[b,s] = dot(proj[b,s,:], h[b,:]); mask positions 1..len-1 to -inf (faithful to ref)
__global__ void attn_scores(const float* __restrict__ proj, const float* __restrict__ h,
                            const int* __restrict__ lens, float* __restrict__ e){
  int bs = blockIdx.x;             // Bn*Sn blocks of 64
  int b = bs / Sn, s = bs % Sn;
  int lane = threadIdx.x;
  const float* row = proj + (size_t)bs*Hn;
  const float* hb  = h + (size_t)b*Hn;
  float acc = 0.f;
  for (int k=lane;k<Hn;k+=64) acc += row[k]*hb[k];
#pragma unroll
  for (int off=32; off>0; off>>=1) acc += __shfl_down(acc, off);
  if (lane==0){
    int len = lens[b];
    bool masked = (s>=1 && s<len);
    e[bs] = masked ? -INFINITY : acc;
  }
}

// softmax over S per batch, then a[b,d] = sum_s alpha[b,s]*encH[b,s,d], d in [0,2H)
__global__ void attn_ctx(const float* __restrict__ e, const float* __restrict__ encH,
                         float* __restrict__ a){
  int b = blockIdx.x;
  __shared__ float sal[Sn+1];
  if (threadIdx.x==0){
    float m=-INFINITY;
    for (int s=0;s<Sn;++s) m = fmaxf(m, e[b*Sn+s]);
    float sum=0.f;
    for (int s=0;s<Sn;++s){ float v=__expf(e[b*Sn+s]-m); sal[s]=v; sum+=v; }
    sal[Sn]=sum;
  }
  __syncthreads();
  float inv = 1.f/sal[Sn];
  for (int d=threadIdx.x; d<2*Hn; d+=blockDim.x){
    float acc=0.f;
    for (int s=0;s<Sn;++s) acc += sal[s]*encH[((size_t)(b*Sn+s))*2*Hn + d];
    a[(size_t)b*2*Hn + d] = acc*inv;
  }
}

// O[b,u] = tanh(bcomb[u] + dot(h[b],Wcomb[u,0:H]) + dot(a[b],Wcomb[u,H:3H]))
__global__ void dec_combine(const float* __restrict__ h, const float* __restrict__ a,
                            const float* __restrict__ Wcomb, const float* __restrict__ bcomb,
                            float* __restrict__ O){
  int tid = blockIdx.x*blockDim.x+threadIdx.x;   // Bn*Hn
  int u = tid % Hn, b = tid / Hn;
  float acc = bcomb[u];
  const float4* hrow=(const float4*)(h + (size_t)b*Hn);
  const float4* arow=(const float4*)(a + (size_t)b*2*Hn);
  const float4* w=(const float4*)(Wcomb + (size_t)u*3*Hn);
#pragma unroll 4
  for (int k=0;k<Hn/4;++k) acc += dot4(hrow[k], w[k]);
#pragma unroll 4
  for (int k=0;k<2*Hn/4;++k) acc += dot4(arow[k], w[Hn/4+k]);
  O[tid] = tanhf(acc);
}

// 128x128 tile GEMM over [R=2560, K=512] x [VT=32000, K]^T with fused per-tile (max,sumexp)
__global__ __launch_bounds__(256) void vocab_gemm(const float* __restrict__ A,
                                                  const float* __restrict__ Wv,
                                                  const float* __restrict__ bv,
                                                  float* __restrict__ stats){
  __shared__ float As[8][128];
  __shared__ float Bs[8][128];
  const int vb = blockIdx.x;       // 0..249
  const int rb = blockIdx.y;       // 0..19
  const int r0 = rb*128, v0 = vb*128;
  const int tid = threadIdx.x;
  const int tx = tid & 15, ty = tid >> 4;
  const int lm = tid >> 1;
  const int lk = (tid & 1) * 4;
  const float* Arow = A  + (size_t)(r0+lm)*Hn + lk;
  const float* Brow = Wv + (size_t)(v0+lm)*Hn + lk;
  float acc[8][8];
#pragma unroll
  for (int i=0;i<8;++i)
#pragma unroll
    for (int j=0;j<8;++j) acc[i][j]=0.f;

  for (int kk=0; kk<Hn; kk+=8){
    float4 av = *(const float4*)(Arow + kk);
    float4 bw = *(const float4*)(Brow + kk);
    __syncthreads();
    As[lk+0][lm]=av.x; As[lk+1][lm]=av.y; As[lk+2][lm]=av.z; As[lk+3][lm]=av.w;
    Bs[lk+0][lm]=bw.x; Bs[lk+1][lm]=bw.y; Bs[lk+2][lm]=bw.z; Bs[lk+3][lm]=bw.w;
    __syncthreads();
#pragma unroll
    for (int k=0;k<8;++k){
      float ra[8], rb_[8];
#pragma unroll
      for (int i=0;i<8;++i) ra[i]=As[k][ty*8+i];
#pragma unroll
      for (int j=0;j<8;++j) rb_[j]=Bs[k][tx*8+j];
#pragma unroll
      for (int i=0;i<8;++i)
#pragma unroll
        for (int j=0;j<8;++j) acc[i][j] += ra[i]*rb_[j];
    }
  }
  float bj[8];
#pragma unroll
  for (int j=0;j<8;++j) bj[j]=bv[v0+tx*8+j];
#pragma unroll
  for (int i=0;i<8;++i){
    int m = ty*8+i;
    float mx = -INFINITY;
#pragma unroll
    for (int j=0;j<8;++j){ acc[i][j]+=bj[j]; mx=fmaxf(mx,acc[i][j]); }
#pragma unroll
    for (int off=1; off<16; off<<=1) mx = fmaxf(mx, __shfl_xor(mx, off));
    float se=0.f;
#pragma unroll
    for (int j=0;j<8;++j) se += __expf(acc[i][j]-mx);
#pragma unroll
    for (int off=1; off<16; off<<=1) se += __shfl_xor(se, off);
    if (tx==0){
      size_t o = ((size_t)(r0+m)*NVB + vb)*2;
      stats[o]   = mx;
      stats[o+1] = se;
    }
  }
}

__global__ void row_lse(const float* __restrict__ stats, float* __restrict__ lse){
  int r = blockIdx.x*blockDim.x+threadIdx.x;
  if (r>=Rn) return;
  const float* st = stats + (size_t)r*NVB*2;
  float M=-INFINITY;
  for (int c=0;c<NVB;++c) M = fmaxf(M, st[2*c]);
  float S=0.f;
  for (int c=0;c<NVB;++c) S += __expf(st[2*c]-M)*st[2*c+1];
  lse[r] = M + logf(S);
}

// nll[r] = lse[r] - (dot(A[r,:], Wv[tgt]) + bv[tgt]);  r = t*B + b, tgt = target[b,t]
__global__ void tgt_nll(const float* __restrict__ A, const float* __restrict__ Wv,
                        const float* __restrict__ bv, const int* __restrict__ tgt,
                        const float* __restrict__ lse, float* __restrict__ nll){
  int r = blockIdx.x;         // Rn blocks of 64
  int t = r / Bn, b = r % Bn;
  int v = tgt[b*Tn + t];
  int lane = threadIdx.x;
  const float* ar = A + (size_t)r*Hn;
  const float* wr = Wv + (size_t)v*Hn;
  float acc=0.f;
  for (int k=lane;k<Hn;k+=64) acc += ar[k]*wr[k];
#pragma unroll
  for (int off=32; off>0; off>>=1) acc += __shfl_down(acc, off);
  if (lane==0) nll[r] = lse[r] - (acc + bv[v]);
}

__global__ void final_mean(const float* __restrict__ nll, float* __restrict__ out){
  __shared__ float red[256];
  float acc=0.f;
  for (int i=threadIdx.x;i<Rn;i+=256) acc += nll[i];
  red[threadIdx.x]=acc;
  __syncthreads();
  for (int off=128; off>0; off>>=1){
    if (threadIdx.x<off) red[threadIdx.x]+=red[threadIdx.x+off];
    __syncthreads();
  }
  if (threadIdx.x==0) out[0] = red[0] / (float)Rn;
}

extern "C" void kernel_launch(void* const* d_in, const int* in_sizes, int n_in,
                              void* d_out, int out_size, void* d_ws, size_t ws_size,
                              hipStream_t stream){
  (void)in_sizes; (void)n_in; (void)out_size; (void)ws_size;
  const int*   srcP  = (const int*)  d_in[0];
  const int*   tgtP  = (const int*)  d_in[1];
  const int*   lens  = (const int*)  d_in[2];
  const float* semb  = (const float*)d_in[3];
  const float* temb  = (const float*)d_in[4];
  const float* Wih_f = (const float*)d_in[5];
  const float* Whh_f = (const float*)d_in[6];
  const float* b_f   = (const float*)d_in[7];
  const float* Wih_b = (const float*)d_in[8];
  const float* Whh_b = (const float*)d_in[9];
  const float* b_b   = (const float*)d_in[10];
  const float* Wih_d = (const float*)d_in[11];
  const float* Whh_d = (const float*)d_in[12];
  const float* b_d   = (const float*)d_in[13];
  const float* Whp   = (const float*)d_in[14];
  const float* bhp   = (const float*)d_in[15];
  const float* Wcp   = (const float*)d_in[16];
  const float* bcp   = (const float*)d_in[17];
  const float* Watt  = (const float*)d_in[18];
  const float* batt  = (const float*)d_in[19];
  const float* Wcomb = (const float*)d_in[20];
  const float* bcomb = (const float*)d_in[21];
  const float* Wvoc  = (const float*)d_in[22];
  const float* bvoc  = (const float*)d_in[23];

  float* w = (float*)d_ws;
  size_t off=0;
  auto alloc=[&](size_t n){ float* p = w+off; off+=n; return p; };
  const size_t BH = (size_t)Bn*Hn;
  float* X    = alloc((size_t)Bn*Sn*En);
  float* Xr   = alloc((size_t)Bn*Sn*En);
  float* encH = alloc((size_t)Bn*Sn*2*Hn);
  float* outR = alloc((size_t)Bn*Sn*Hn);
  float* eprj = alloc((size_t)Bn*Sn*Hn);
  float* outs = alloc((size_t)Tn*Bn*Hn);
  float* small= alloc(10*BH);
  float* e    = alloc((size_t)Bn*Sn);
  float* actx = alloc((size_t)Bn*2*Hn);
  float* stats= alloc((size_t)Rn*NVB*2);
  float* lse  = alloc(Rn);
  float* nll  = alloc(Rn);

  float* hF[2] = { small + 0*BH, small + 1*BH };
  float* cF    =   small + 2*BH;
  float* hB[2] = { small + 3*BH, small + 4*BH };
  float* cB    =   small + 5*BH;
  float* dH[2] = { small + 6*BH, small + 7*BH };
  float* dC    =   small + 8*BH;
  float* o0    =   small + 9*BH;

  // zero states (h,c,o0)
  {
    int n4 = (int)(10*BH/4);
    zero_f4<<<(n4+255)/256, 256, 0, stream>>>((float4*)small, n4);
  }
  // embeddings (fwd + reversed)
  {
    int tot = Bn*Sn*(En/4);
    embed_src<<<(tot+255)/256, 256, 0, stream>>>(srcP, lens, semb, X, Xr);
  }
  // encoder forward scan -> encH[...,0:H]
  for (int s=0;s<Sn;++s)
    enc_lstm_step<<<(Bn*Hn)/256, 256, 0, stream>>>(X, Wih_f, Whh_f, b_f,
        hF[s&1], hF[(s+1)&1], cF, encH, 2*Hn, lens, s);
  // encoder backward scan on reversed input -> outR
  for (int s=0;s<Sn;++s)
    enc_lstm_step<<<(Bn*Hn)/256, 256, 0, stream>>>(Xr, Wih_b, Whh_b, b_b,
        hB[s&1], hB[(s+1)&1], cB, outR, Hn, lens, s);
  // un-reverse backward outputs -> encH[...,H:2H]
  {
    int tot = Bn*Sn*(Hn/4);
    reverse_bwd<<<(tot+255)/256, 256, 0, stream>>>(outR, lens, encH);
  }
  // decoder init projections (final states are in buffer 0: Sn=40 even)
  proj_cat<<<(Bn*Hn)/256, 256, 0, stream>>>(hF[0], hB[0], Whp, bhp, dH[0]);
  proj_cat<<<(Bn*Hn)/256, 256, 0, stream>>>(cF,    cB,    Wcp, bcp, dC);
  // attention projection of encoder states
  {
    int tot = Bn*Sn*Hn;
    enc_proj_k<<<tot/256, 256, 0, stream>>>(encH, Watt, batt, eprj);
  }
  // decoder scan
  for (int t=0;t<Tn;++t){
    const float* oprev = (t==0) ? o0 : (outs + (size_t)(t-1)*BH);
    float* hcur = dH[(t+1)&1];
    dec_lstm_step<<<(Bn*Hn)/256, 256, 0, stream>>>(tgtP, temb, oprev,
        Wih_d, Whh_d, b_d, dH[t&1], hcur, dC, t);
    attn_scores<<<Bn*Sn, 64, 0, stream>>>(eprj, hcur, lens, e);
    attn_ctx<<<Bn, 256, 0, stream>>>(e, encH, actx);
    dec_combine<<<(Bn*Hn)/256, 256, 0, stream>>>(hcur, actx, Wcomb, bcomb,
        outs + (size_t)t*BH);
  }
  // vocab projection with fused chunk stats
  vocab_gemm<<<dim3(NVB, Rn/128), 256, 0, stream>>>(outs, Wvoc, bvoc, stats);
  row_lse<<<(Rn+255)/256, 256, 0, stream>>>(stats, lse);
  tgt_nll<<<Rn, 64, 0, stream>>>(outs, Wvoc, bvoc, tgtP, lse, nll);
  final_mean<<<1, 256, 0, stream>>>(nll, (float*)d_out);
}

// Round 2
// 3602.525 us; speedup vs baseline: 5.6315x; 5.6315x over previous
//
#include <hip/hip_runtime.h>
#include <math.h>

#define En 256
#define Hn 512
#define Bn 64
#define Sn 40
#define Tn 40
#define VTn 32000
#define Rn (Tn*Bn)
#define NVB 250   // 32000 / 128

__device__ __forceinline__ float dot4(float4 a, float4 b){
  return a.x*b.x + a.y*b.y + a.z*b.z + a.w*b.w;
}
__device__ __forceinline__ float sigm(float x){ return 1.f/(1.f+__expf(-x)); }

__global__ void zero_f4(float4* p, int n4){
  int i = blockIdx.x*blockDim.x+threadIdx.x;
  if (i<n4) p[i]=make_float4(0.f,0.f,0.f,0.f);
}

// grev[b*Sn+s] = (len-1-s>=0) ? src[b*Sn + len-1-s] : -1
// gtgt[t*Bn+b] = tgt[b*Tn + t]
__global__ void build_maps(const int* __restrict__ src, const int* __restrict__ tgt,
                           const int* __restrict__ lens, int* __restrict__ grev,
                           int* __restrict__ gtgt){
  int r = blockIdx.x*blockDim.x+threadIdx.x;
  if (r >= Bn*Sn) return;
  int b = r / Sn, s = r % Sn;
  int j = lens[b]-1-s;
  grev[r] = (j>=0) ? src[b*Sn+j] : -1;
  int t2 = r >> 6, b2 = r & 63;   // Rn == Bn*Sn == 2560
  gtgt[r] = tgt[b2*Tn + t2];
}

// C[M,N] = gatherRows(A)[M,lda] @ B[N,ldb]^T + bias ; 128x128 tiles, BK=8
__global__ __launch_bounds__(256) void gemm128(const float* __restrict__ A, int lda,
                                               const int* __restrict__ gather,
                                               const float* __restrict__ B, int ldb,
                                               const float* __restrict__ bias,
                                               float* __restrict__ C, int ldc, int K){
  __shared__ float As[8][128];
  __shared__ float Bs[8][128];
  const int n0 = blockIdx.x*128, r0 = blockIdx.y*128;
  const int tid = threadIdx.x;
  const int tx = tid & 15, ty = tid >> 4;
  const int lm = tid >> 1, lk = (tid & 1)*4;
  int ar = gather ? gather[r0+lm] : (r0+lm);
  const float* Arow = (ar>=0) ? (A + (size_t)ar*lda + lk) : nullptr;
  const float* Brow = B + (size_t)(n0+lm)*ldb + lk;
  float acc[8][8];
#pragma unroll
  for (int i=0;i<8;++i)
#pragma unroll
    for (int j=0;j<8;++j) acc[i][j]=0.f;

  for (int kk=0; kk<K; kk+=8){
    float4 av = Arow ? *(const float4*)(Arow + kk) : make_float4(0.f,0.f,0.f,0.f);
    float4 bw = *(const float4*)(Brow + kk);
    __syncthreads();
    As[lk+0][lm]=av.x; As[lk+1][lm]=av.y; As[lk+2][lm]=av.z; As[lk+3][lm]=av.w;
    Bs[lk+0][lm]=bw.x; Bs[lk+1][lm]=bw.y; Bs[lk+2][lm]=bw.z; Bs[lk+3][lm]=bw.w;
    __syncthreads();
#pragma unroll
    for (int k=0;k<8;++k){
      float4 a0 = *(const float4*)&As[k][ty*8];
      float4 a1 = *(const float4*)&As[k][ty*8+4];
      float4 b0 = *(const float4*)&Bs[k][tx*4];
      float4 b1 = *(const float4*)&Bs[k][64+tx*4];
      float am[8]={a0.x,a0.y,a0.z,a0.w,a1.x,a1.y,a1.z,a1.w};
      float bm[8]={b0.x,b0.y,b0.z,b0.w,b1.x,b1.y,b1.z,b1.w};
#pragma unroll
      for (int i=0;i<8;++i)
#pragma unroll
        for (int j=0;j<8;++j) acc[i][j] += am[i]*bm[j];
    }
  }
  float4 bb0 = *(const float4*)&bias[n0+tx*4];
  float4 bb1 = *(const float4*)&bias[n0+64+tx*4];
#pragma unroll
  for (int i=0;i<8;++i){
    int r = r0 + ty*8 + i;
    float4 o0 = make_float4(acc[i][0]+bb0.x, acc[i][1]+bb0.y, acc[i][2]+bb0.z, acc[i][3]+bb0.w);
    float4 o1 = make_float4(acc[i][4]+bb1.x, acc[i][5]+bb1.y, acc[i][6]+bb1.z, acc[i][7]+bb1.w);
    *(float4*)(C + (size_t)r*ldc + n0 + tx*4)      = o0;
    *(float4*)(C + (size_t)r*ldc + n0 + 64 + tx*4) = o1;
  }
}

// Encoder recurrent partial GEMM: penc[dir][ksp][b][n] = h_dir[b,:] (k-chunk) @ Whh_dir^T
// grid (16 n-tiles of 128, 8 k-splits of 64, 2 dirs), block 256
__global__ __launch_bounds__(256) void enc_partial(const float* __restrict__ hf,
                                                   const float* __restrict__ hb,
                                                   const float* __restrict__ Wf,
                                                   const float* __restrict__ Wb,
                                                   float* __restrict__ penc){
  const int dir = blockIdx.z;
  const float* h = dir ? hb : hf;
  const float* W = dir ? Wb : Wf;
  const int n0 = blockIdx.x*128;
  const int k0 = blockIdx.y*64;
  __shared__ float As[8][64];
  __shared__ float Bs[8][128];
  const int tid = threadIdx.x;
  const int ty = tid>>5, tx = tid&31;
  float acc[8][4];
#pragma unroll
  for (int i=0;i<8;++i){ acc[i][0]=0.f;acc[i][1]=0.f;acc[i][2]=0.f;acc[i][3]=0.f; }
  for (int kk=0; kk<64; kk+=8){
    __syncthreads();
    if (tid < 128){
      int lm = tid>>1, lk = (tid&1)*4;
      float4 v = *(const float4*)(h + (size_t)lm*Hn + k0+kk+lk);
      As[lk+0][lm]=v.x; As[lk+1][lm]=v.y; As[lk+2][lm]=v.z; As[lk+3][lm]=v.w;
    } else {
      int t2 = tid-128;
      const float* wr = W + (size_t)(n0+t2)*Hn + k0+kk;
      float4 v0 = *(const float4*)(wr);
      float4 v1 = *(const float4*)(wr+4);
      Bs[0][t2]=v0.x; Bs[1][t2]=v0.y; Bs[2][t2]=v0.z; Bs[3][t2]=v0.w;
      Bs[4][t2]=v1.x; Bs[5][t2]=v1.y; Bs[6][t2]=v1.z; Bs[7][t2]=v1.w;
    }
    __syncthreads();
#pragma unroll
    for (int k=0;k<8;++k){
      float4 a0 = *(const float4*)&As[k][ty*8];
      float4 a1 = *(const float4*)&As[k][ty*8+4];
      float4 bv = *(const float4*)&Bs[k][tx*4];
      float am[8]={a0.x,a0.y,a0.z,a0.w,a1.x,a1.y,a1.z,a1.w};
      float bm[4]={bv.x,bv.y,bv.z,bv.w};
#pragma unroll
      for (int i=0;i<8;++i)
#pragma unroll
        for (int j=0;j<4;++j) acc[i][j] += am[i]*bm[j];
    }
  }
  float* out = penc + ((size_t)(dir*8 + blockIdx.y)*64)*2048;
#pragma unroll
  for (int i=0;i<8;++i)
    *(float4*)(out + (size_t)(ty*8+i)*2048 + n0 + tx*4) =
        make_float4(acc[i][0],acc[i][1],acc[i][2],acc[i][3]);
}

// Encoder reduce + LSTM activation, both dirs. grid 256 x 256.
__global__ void enc_reduce(const float* __restrict__ penc,
                           const float* __restrict__ Gf, const float* __restrict__ Gb,
                           const float* __restrict__ hin_f, float* __restrict__ hout_f,
                           float* __restrict__ c_f,
                           const float* __restrict__ hin_b, float* __restrict__ hout_b,
                           float* __restrict__ c_b,
                           float* __restrict__ encH, float* __restrict__ outR,
                           const int* __restrict__ lens, int s){
  int t = blockIdx.x*blockDim.x + threadIdx.x;   // 2*64*512
  int u = t & 511, b = (t>>9) & 63, dir = t>>15;
  const float* Gin = dir ? Gb : Gf;
  const float* pe = penc + (size_t)dir*8*64*2048;
  float g[4];
#pragma unroll
  for (int gi=0; gi<4; ++gi){
    int n = gi*512 + u;
    float acc = Gin[((size_t)(b*Sn+s))*2048 + n];
#pragma unroll
    for (int ks=0; ks<8; ++ks) acc += pe[((size_t)ks*64 + b)*2048 + n];
    g[gi] = acc;
  }
  const float* hin = dir ? hin_b : hin_f;
  float* hout = dir ? hout_b : hout_f;
  float* c    = dir ? c_b : c_f;
  int bu = b*512 + u;
  float ig=sigm(g[0]), fg=sigm(g[1]), gg=tanhf(g[2]), og=sigm(g[3]);
  float cp = c[bu];
  float cn = fg*cp + ig*gg;
  float hn = og*tanhf(cn);
  bool valid = s < lens[b];
  hout[bu] = valid ? hn : hin[bu];
  c[bu]    = valid ? cn : cp;
  if (dir==0) encH[((size_t)(b*Sn+s))*1024 + u] = valid ? hn : 0.f;
  else        outR[((size_t)(b*Sn+s))*512  + u] = valid ? hn : 0.f;
}

__global__ void reverse_bwd(const float* __restrict__ outR, const int* __restrict__ lens,
                            float* __restrict__ encH){
  int idx = blockIdx.x*blockDim.x+threadIdx.x;
  const int tot = Bn*Sn*(Hn/4);
  if (idx>=tot) return;
  int u4 = idx % (Hn/4);
  int bs = idx / (Hn/4);
  int s = bs % Sn, b = bs / Sn;
  int len = lens[b];
  float4 v = make_float4(0.f,0.f,0.f,0.f);
  if (s < len){
    int j = len-1-s;
    v = ((const float4*)(outR + ((size_t)(b*Sn+j))*Hn))[u4];
  }
  ((float4*)(encH + ((size_t)(b*Sn+s))*2*Hn + Hn))[u4] = v;
}

__global__ void proj_cat(const float* __restrict__ x1, const float* __restrict__ x2,
                         const float* __restrict__ W, const float* __restrict__ bias,
                         float* __restrict__ y){
  int tid = blockIdx.x*blockDim.x+threadIdx.x;   // Bn*Hn
  int u = tid % Hn, b = tid / Hn;
  float acc = bias[u];
  const float4* a1 = (const float4*)(x1 + (size_t)b*Hn);
  const float4* a2 = (const float4*)(x2 + (size_t)b*Hn);
  const float4* w  = (const float4*)(W + (size_t)u*2*Hn);
#pragma unroll 4
  for (int k=0;k<Hn/4;++k) acc += dot4(a1[k], w[k]);
#pragma unroll 4
  for (int k=0;k<Hn/4;++k) acc += dot4(a2[k], w[Hn/4+k]);
  y[tid]=acc;
}

// Decoder LSTM recurrent partial: k=1024 = [h (512) | o_prev (512)]
// grid (16 n-tiles of 128, 16 k-splits of 64), block 256
__global__ __launch_bounds__(256) void dec_partial(const float* __restrict__ hprev,
                                                   const float* __restrict__ oprev,
                                                   const float* __restrict__ Whh,
                                                   const float* __restrict__ Wih,
                                                   float* __restrict__ pdec){
  const int n0 = blockIdx.x*128;
  const int k0 = blockIdx.y*64;
  const float* A; int acol; const float* Bb; int ldb; int bcol;
  if (k0 < 512){ A = hprev; acol = k0;      Bb = Whh; ldb = Hn;    bcol = k0; }
  else         { A = oprev; acol = k0-512;  Bb = Wih; ldb = En+Hn; bcol = En + (k0-512); }
  __shared__ float As[8][64];
  __shared__ float Bs[8][128];
  const int tid = threadIdx.x;
  const int ty = tid>>5, tx = tid&31;
  float acc[8][4];
#pragma unroll
  for (int i=0;i<8;++i){ acc[i][0]=0.f;acc[i][1]=0.f;acc[i][2]=0.f;acc[i][3]=0.f; }
  for (int kk=0; kk<64; kk+=8){
    __syncthreads();
    if (tid < 128){
      int lm = tid>>1, lk = (tid&1)*4;
      float4 v = *(const float4*)(A + (size_t)lm*Hn + acol+kk+lk);
      As[lk+0][lm]=v.x; As[lk+1][lm]=v.y; As[lk+2][lm]=v.z; As[lk+3][lm]=v.w;
    } else {
      int t2 = tid-128;
      const float* wr = Bb + (size_t)(n0+t2)*ldb + bcol+kk;
      float4 v0 = *(const float4*)(wr);
      float4 v1 = *(const float4*)(wr+4);
      Bs[0][t2]=v0.x; Bs[1][t2]=v0.y; Bs[2][t2]=v0.z; Bs[3][t2]=v0.w;
      Bs[4][t2]=v1.x; Bs[5][t2]=v1.y; Bs[6][t2]=v1.z; Bs[7][t2]=v1.w;
    }
    __syncthreads();
#pragma unroll
    for (int k=0;k<8;++k){
      float4 a0 = *(const float4*)&As[k][ty*8];
      float4 a1 = *(const float4*)&As[k][ty*8+4];
      float4 bv = *(const float4*)&Bs[k][tx*4];
      float am[8]={a0.x,a0.y,a0.z,a0.w,a1.x,a1.y,a1.z,a1.w};
      float bm[4]={bv.x,bv.y,bv.z,bv.w};
#pragma unroll
      for (int i=0;i<8;++i)
#pragma unroll
        for (int j=0;j<4;++j) acc[i][j] += am[i]*bm[j];
    }
  }
  float* out = pdec + (size_t)blockIdx.y*64*2048;
#pragma unroll
  for (int i=0;i<8;++i)
    *(float4*)(out + (size_t)(ty*8+i)*2048 + n0 + tx*4) =
        make_float4(acc[i][0],acc[i][1],acc[i][2],acc[i][3]);
}

// Decoder LSTM reduce + activation. grid 128 x 256.
__global__ void dec_reduce(const float* __restrict__ pdec, const float* __restrict__ Gdy,
                           float* __restrict__ hout, float* __restrict__ c, int tstep){
  int t = blockIdx.x*blockDim.x + threadIdx.x;   // 64*512
  int u = t & 511, b = t>>9;
  float g[4];
#pragma unroll
  for (int gi=0; gi<4; ++gi){
    int n = gi*512 + u;
    float acc = Gdy[((size_t)(tstep*Bn+b))*2048 + n];
#pragma unroll
    for (int ks=0; ks<16; ++ks) acc += pdec[((size_t)ks*64 + b)*2048 + n];
    g[gi] = acc;
  }
  int bu = b*512 + u;
  float ig=sigm(g[0]), fg=sigm(g[1]), gg=tanhf(g[2]), og=sigm(g[3]);
  float cp = c[bu];
  float cn = fg*cp + ig*gg;
  float hn = og*tanhf(cn);
  hout[bu] = hn;
  c[bu] = cn;
}

// Fused attention: scores + softmax + context. grid 64 x 256.
__global__ __launch_bounds__(256) void attn_step(const float* __restrict__ eprj,
                                                 const float* __restrict__ encH,
                                                 const float* __restrict__ h,
                                                 const int* __restrict__ lens,
                                                 float* __restrict__ actx){
  const int b = blockIdx.x;
  __shared__ float hs[512];
  __shared__ float es[Sn];
  __shared__ float sal[Sn];
  __shared__ float sinv_s;
  const int tid = threadIdx.x;
  if (tid < 128) *(float4*)&hs[tid*4] = *(const float4*)(h + (size_t)b*Hn + tid*4);
  __syncthreads();
  const int w = tid>>6, lane = tid&63;
  const int len = lens[b];
  for (int si=0; si<10; ++si){
    int s = w*10 + si;
    const float* pr = eprj + ((size_t)(b*Sn+s))*Hn + lane*8;
    float4 p0 = *(const float4*)pr, p1 = *(const float4*)(pr+4);
    const float* hh = hs + lane*8;
    float4 h0 = *(const float4*)hh, h1 = *(const float4*)(hh+4);
    float acc = dot4(p0,h0) + dot4(p1,h1);
#pragma unroll
    for (int off=32; off; off>>=1) acc += __shfl_down(acc, off);
    if (lane==0) es[s] = (s>=1 && s<len) ? -INFINITY : acc;
  }
  __syncthreads();
  if (tid < 64){
    float e = (tid<Sn) ? es[tid] : -INFINITY;
    float m = e;
#pragma unroll
    for (int off=32; off; off>>=1) m = fmaxf(m, __shfl_xor(m, off));
    float p = (tid<Sn) ? __expf(e-m) : 0.f;
    float sum = p;
#pragma unroll
    for (int off=32; off; off>>=1) sum += __shfl_xor(sum, off);
    if (tid<Sn) sal[tid] = p;
    if (tid==0) sinv_s = 1.f/sum;
  }
  __syncthreads();
  float inv = sinv_s;
#pragma unroll
  for (int dq=0; dq<4; ++dq){
    int d = dq*256 + tid;
    float acc = 0.f;
    for (int s=0;s<Sn;++s) acc += sal[s]*encH[((size_t)(b*Sn+s))*1024 + d];
    actx[(size_t)b*1024 + d] = acc*inv;
  }
}

// Combine partial: O-pre = [h | a] @ Wcomb^T ; grid (8 n-tiles of 64, 24 k-splits of 64)
__global__ __launch_bounds__(256) void comb_partial(const float* __restrict__ hcur,
                                                    const float* __restrict__ actx,
                                                    const float* __restrict__ Wcomb,
                                                    float* __restrict__ pcomb){
  const int n0 = blockIdx.x*64;
  const int k0 = blockIdx.y*64;
  const float* A; int lda; int acol;
  if (k0 < 512){ A = hcur; lda = Hn;   acol = k0; }
  else         { A = actx; lda = 2*Hn; acol = k0-512; }
  __shared__ float As[8][64];
  __shared__ float Bs[8][64];
  const int tid = threadIdx.x;
  const int ty = tid>>4, tx = tid&15;
  float acc[4][4];
#pragma unroll
  for (int i=0;i<4;++i){ acc[i][0]=0.f;acc[i][1]=0.f;acc[i][2]=0.f;acc[i][3]=0.f; }
  for (int kk=0; kk<64; kk+=8){
    __syncthreads();
    if (tid < 128){
      int lm = tid>>1, lk = (tid&1)*4;
      float4 v = *(const float4*)(A + (size_t)lm*lda + acol+kk+lk);
      As[lk+0][lm]=v.x; As[lk+1][lm]=v.y; As[lk+2][lm]=v.z; As[lk+3][lm]=v.w;
    } else {
      int t2 = tid-128;
      int lm = t2>>1, lk = (t2&1)*4;
      float4 v = *(const float4*)(Wcomb + (size_t)(n0+lm)*(3*Hn) + k0+kk+lk);
      Bs[lk+0][lm]=v.x; Bs[lk+1][lm]=v.y; Bs[lk+2][lm]=v.z; Bs[lk+3][lm]=v.w;
    }
    __syncthreads();
#pragma unroll
    for (int k=0;k<8;++k){
      float4 av = *(const float4*)&As[k][ty*4];
      float4 bv = *(const float4*)&Bs[k][tx*4];
      float am[4]={av.x,av.y,av.z,av.w};
      float bm[4]={bv.x,bv.y,bv.z,bv.w};
#pragma unroll
      for (int i=0;i<4;++i)
#pragma unroll
        for (int j=0;j<4;++j) acc[i][j] += am[i]*bm[j];
    }
  }
  float* out = pcomb + (size_t)blockIdx.y*64*512;
#pragma unroll
  for (int i=0;i<4;++i)
    *(float4*)(out + (size_t)(ty*4+i)*512 + n0 + tx*4) =
        make_float4(acc[i][0],acc[i][1],acc[i][2],acc[i][3]);
}

// Combine reduce + tanh -> outs[t]. grid 128 x 256.
__global__ void comb_reduce(const float* __restrict__ pcomb, const float* __restrict__ bcomb,
                            float* __restrict__ outs_t){
  int t = blockIdx.x*blockDim.x + threadIdx.x;   // 64*512
  int u = t & 511, b = t>>9;
  float acc = bcomb[u];
#pragma unroll
  for (int kz=0; kz<24; ++kz) acc += pcomb[((size_t)kz*64 + b)*512 + u];
  outs_t[(size_t)b*512 + u] = tanhf(acc);
}

// 128x128 tile GEMM with fused per-tile (max,sumexp); bank-conflict-fixed micro layout.
__global__ __launch_bounds__(256) void vocab_gemm(const float* __restrict__ A,
                                                  const float* __restrict__ Wv,
                                                  const float* __restrict__ bv,
                                                  float* __restrict__ stats){
  __shared__ float As[8][128];
  __shared__ float Bs[8][128];
  const int vb = blockIdx.x;       // 0..249
  const int rb = blockIdx.y;       // 0..19
  const int r0 = rb*128, v0 = vb*128;
  const int tid = threadIdx.x;
  const int tx = tid & 15, ty = tid >> 4;
  const int lm = tid >> 1;
  const int lk = (tid & 1) * 4;
  const float* Arow = A  + (size_t)(r0+lm)*Hn + lk;
  const float* Brow = Wv + (size_t)(v0+lm)*Hn + lk;
  float acc[8][8];
#pragma unroll
  for (int i=0;i<8;++i)
#pragma unroll
    for (int j=0;j<8;++j) acc[i][j]=0.f;

  for (int kk=0; kk<Hn; kk+=8){
    float4 av = *(const float4*)(Arow + kk);
    float4 bw = *(const float4*)(Brow + kk);
    __syncthreads();
    As[lk+0][lm]=av.x; As[lk+1][lm]=av.y; As[lk+2][lm]=av.z; As[lk+3][lm]=av.w;
    Bs[lk+0][lm]=bw.x; Bs[lk+1][lm]=bw.y; Bs[lk+2][lm]=bw.z; Bs[lk+3][lm]=bw.w;
    __syncthreads();
#pragma unroll
    for (int k=0;k<8;++k){
      float4 a0 = *(const float4*)&As[k][ty*8];
      float4 a1 = *(const float4*)&As[k][ty*8+4];
      float4 b0 = *(const float4*)&Bs[k][tx*4];
      float4 b1 = *(const float4*)&Bs[k][64+tx*4];
      float am[8]={a0.x,a0.y,a0.z,a0.w,a1.x,a1.y,a1.z,a1.w};
      float bm[8]={b0.x,b0.y,b0.z,b0.w,b1.x,b1.y,b1.z,b1.w};
#pragma unroll
      for (int i=0;i<8;++i)
#pragma unroll
        for (int j=0;j<8;++j) acc[i][j] += am[i]*bm[j];
    }
  }
  float bj[8];
  {
    float4 bb0 = *(const float4*)&bv[v0+tx*4];
    float4 bb1 = *(const float4*)&bv[v0+64+tx*4];
    bj[0]=bb0.x;bj[1]=bb0.y;bj[2]=bb0.z;bj[3]=bb0.w;
    bj[4]=bb1.x;bj[5]=bb1.y;bj[6]=bb1.z;bj[7]=bb1.w;
  }
#pragma unroll
  for (int i=0;i<8;++i){
    int m = ty*8+i;
    float mx = -INFINITY;
#pragma unroll
    for (int j=0;j<8;++j){ acc[i][j]+=bj[j]; mx=fmaxf(mx,acc[i][j]); }
#pragma unroll
    for (int off=1; off<16; off<<=1) mx = fmaxf(mx, __shfl_xor(mx, off));
    float se=0.f;
#pragma unroll
    for (int j=0;j<8;++j) se += __expf(acc[i][j]-mx);
#pragma unroll
    for (int off=1; off<16; off<<=1) se += __shfl_xor(se, off);
    if (tx==0){
      size_t o = ((size_t)(r0+m)*NVB + vb)*2;
      stats[o]   = mx;
      stats[o+1] = se;
    }
  }
}

__global__ void row_lse(const float* __restrict__ stats, float* __restrict__ lse){
  int r = blockIdx.x*blockDim.x+threadIdx.x;
  if (r>=Rn) return;
  const float* st = stats + (size_t)r*NVB*2;
  float M=-INFINITY;
  for (int c=0;c<NVB;++c) M = fmaxf(M, st[2*c]);
  float S=0.f;
  for (int c=0;c<NVB;++c) S += __expf(st[2*c]-M)*st[2*c+1];
  lse[r] = M + logf(S);
}

__global__ void tgt_nll(const float* __restrict__ A, const float* __restrict__ Wv,
                        const float* __restrict__ bv, const int* __restrict__ tgt,
                        const float* __restrict__ lse, float* __restrict__ nll){
  int r = blockIdx.x;         // Rn blocks of 64
  int t = r / Bn, b = r % Bn;
  int v = tgt[b*Tn + t];
  int lane = threadIdx.x;
  const float* ar = A + (size_t)r*Hn;
  const float* wr = Wv + (size_t)v*Hn;
  float acc=0.f;
  for (int k=lane;k<Hn;k+=64) acc += ar[k]*wr[k];
#pragma unroll
  for (int off=32; off>0; off>>=1) acc += __shfl_down(acc, off);
  if (lane==0) nll[r] = lse[r] - (acc + bv[v]);
}

__global__ void final_mean(const float* __restrict__ nll, float* __restrict__ out){
  __shared__ float red[256];
  float acc=0.f;
  for (int i=threadIdx.x;i<Rn;i+=256) acc += nll[i];
  red[threadIdx.x]=acc;
  __syncthreads();
  for (int off=128; off>0; off>>=1){
    if (threadIdx.x<off) red[threadIdx.x]+=red[threadIdx.x+off];
    __syncthreads();
  }
  if (threadIdx.x==0) out[0] = red[0] / (float)Rn;
}

extern "C" void kernel_launch(void* const* d_in, const int* in_sizes, int n_in,
                              void* d_out, int out_size, void* d_ws, size_t ws_size,
                              hipStream_t stream){
  (void)in_sizes; (void)n_in; (void)out_size; (void)ws_size;
  const int*   srcP  = (const int*)  d_in[0];
  const int*   tgtP  = (const int*)  d_in[1];
  const int*   lens  = (const int*)  d_in[2];
  const float* semb  = (const float*)d_in[3];
  const float* temb  = (const float*)d_in[4];
  const float* Wih_f = (const float*)d_in[5];
  const float* Whh_f = (const float*)d_in[6];
  const float* b_f   = (const float*)d_in[7];
  const float* Wih_b = (const float*)d_in[8];
  const float* Whh_b = (const float*)d_in[9];
  const float* b_b   = (const float*)d_in[10];
  const float* Wih_d = (const float*)d_in[11];
  const float* Whh_d = (const float*)d_in[12];
  const float* b_d   = (const float*)d_in[13];
  const float* Whp   = (const float*)d_in[14];
  const float* bhp   = (const float*)d_in[15];
  const float* Wcp   = (const float*)d_in[16];
  const float* bcp   = (const float*)d_in[17];
  const float* Watt  = (const float*)d_in[18];
  const float* batt  = (const float*)d_in[19];
  const float* Wcomb = (const float*)d_in[20];
  const float* bcomb = (const float*)d_in[21];
  const float* Wvoc  = (const float*)d_in[22];
  const float* bvoc  = (const float*)d_in[23];

  float* w = (float*)d_ws;
  size_t off=0;
  auto alloc=[&](size_t n){ float* p = w+off; off+=n; return p; };
  const size_t BH = (size_t)Bn*Hn;
  float* encH = alloc((size_t)Bn*Sn*2*Hn);
  float* outR = alloc((size_t)Bn*Sn*Hn);
  float* eprj = alloc((size_t)Bn*Sn*Hn);
  float* outs = alloc((size_t)Tn*Bn*Hn);
  float* Gf   = alloc((size_t)Bn*Sn*4*Hn);
  float* Gb   = alloc((size_t)Bn*Sn*4*Hn);
  float* Gdy  = alloc((size_t)Tn*Bn*4*Hn);
  float* penc = alloc((size_t)2*8*64*2048);
  float* pdec = alloc((size_t)16*64*2048);
  float* pcomb= alloc((size_t)24*64*512);
  float* small= alloc(10*BH);
  float* actx = alloc((size_t)Bn*2*Hn);
  float* stats= alloc((size_t)Rn*NVB*2);
  float* lse  = alloc(Rn);
  float* nll  = alloc(Rn);
  int* grev = (int*)alloc(Bn*Sn);
  int* gtgt = (int*)alloc(Tn*Bn);

  float* hF[2] = { small + 0*BH, small + 1*BH };
  float* cF    =   small + 2*BH;
  float* hB[2] = { small + 3*BH, small + 4*BH };
  float* cB    =   small + 5*BH;
  float* dH[2] = { small + 6*BH, small + 7*BH };
  float* dC    =   small + 8*BH;
  float* o0    =   small + 9*BH;

  {
    int n4 = (int)(10*BH/4);
    zero_f4<<<(n4+255)/256, 256, 0, stream>>>((float4*)small, n4);
  }
  build_maps<<<(Bn*Sn+255)/256, 256, 0, stream>>>(srcP, tgtP, lens, grev, gtgt);

  // input-side gate precompute
  gemm128<<<dim3(16,20), 256, 0, stream>>>(semb, En, srcP, Wih_f, En, b_f, Gf, 4*Hn, En);
  gemm128<<<dim3(16,20), 256, 0, stream>>>(semb, En, grev, Wih_b, En, b_b, Gb, 4*Hn, En);
  gemm128<<<dim3(16,20), 256, 0, stream>>>(temb, En, gtgt, Wih_d, En+Hn, b_d, Gdy, 4*Hn, En);

  // encoder scans (both directions fused)
  for (int s=0;s<Sn;++s){
    enc_partial<<<dim3(16,8,2), 256, 0, stream>>>(hF[s&1], hB[s&1], Whh_f, Whh_b, penc);
    enc_reduce<<<256, 256, 0, stream>>>(penc, Gf, Gb,
        hF[s&1], hF[(s+1)&1], cF, hB[s&1], hB[(s+1)&1], cB, encH, outR, lens, s);
  }
  {
    int tot = Bn*Sn*(Hn/4);
    reverse_bwd<<<(tot+255)/256, 256, 0, stream>>>(outR, lens, encH);
  }
  proj_cat<<<(Bn*Hn)/256, 256, 0, stream>>>(hF[0], hB[0], Whp, bhp, dH[0]);
  proj_cat<<<(Bn*Hn)/256, 256, 0, stream>>>(cF,    cB,    Wcp, bcp, dC);
  // attention projection of encoder states
  gemm128<<<dim3(4,20), 256, 0, stream>>>(encH, 2*Hn, nullptr, Watt, 2*Hn, batt, eprj, Hn, 2*Hn);

  // decoder scan
  for (int t=0;t<Tn;++t){
    const float* oprev = (t==0) ? o0 : (outs + (size_t)(t-1)*BH);
    float* hcur = dH[(t+1)&1];
    dec_partial<<<dim3(16,16), 256, 0, stream>>>(dH[t&1], oprev, Whh_d, Wih_d, pdec);
    dec_reduce<<<128, 256, 0, stream>>>(pdec, Gdy, hcur, dC, t);
    attn_step<<<Bn, 256, 0, stream>>>(eprj, encH, hcur, lens, actx);
    comb_partial<<<dim3(8,24), 256, 0, stream>>>(hcur, actx, Wcomb, pcomb);
    comb_reduce<<<128, 256, 0, stream>>>(pcomb, bcomb, outs + (size_t)t*BH);
  }

  vocab_gemm<<<dim3(NVB, Rn/128), 256, 0, stream>>>(outs, Wvoc, bvoc, stats);
  row_lse<<<(Rn+255)/256, 256, 0, stream>>>(stats, lse);
  tgt_nll<<<Rn, 64, 0, stream>>>(outs, Wvoc, bvoc, tgtP, lse, nll);
  final_mean<<<1, 256, 0, stream>>>(nll, (float*)d_out);
}